// Round 1
// baseline (793.781 us; speedup 1.0000x reference)
//
#include <hip/hip_runtime.h>
#include <cstdint>
#include <cstddef>

typedef unsigned short u16;
typedef __attribute__((ext_vector_type(8))) __bf16 bf16x8;
typedef __attribute__((ext_vector_type(4))) float f32x4;

#define DEV __device__ __forceinline__

DEV u16 f2bf(float f) {
  unsigned u = __float_as_uint(f);
  return (u16)((u + 0x7FFFu + ((u >> 16) & 1u)) >> 16);
}

DEV void glds16(const void* g, void* l) {
  __builtin_amdgcn_global_load_lds((const __attribute__((address_space(1))) void*)g,
                                   (__attribute__((address_space(3))) void*)l,
                                   16, 0, 0);
}

// ---------------------------------------------------------------- prep kernels

__global__ void zero4_kernel(float* p) {
  int t = threadIdx.x;
  if (t < 4) p[t] = 0.f;
}

// contiguous fp32 -> bf16 convert, vectorized x4, grid-stride
__global__ void conv_cat(const float* __restrict__ s, u16* __restrict__ d, long n4) {
  long stride = (long)gridDim.x * blockDim.x;
  for (long i = blockIdx.x * (long)blockDim.x + threadIdx.x; i < n4; i += stride) {
    float4 v = *(const float4*)(s + i * 4);
    *(ushort4*)(d + i * 4) = make_ushort4(f2bf(v.x), f2bf(v.y), f2bf(v.z), f2bf(v.w));
  }
}

// [2048][1024] fp32 -> bf16 into dst with leading dim dld (for concat buffers)
__global__ void conv_strided(const float* __restrict__ s, u16* __restrict__ d, int dld) {
  int t = blockIdx.x * blockDim.x + threadIdx.x;  // 524288 threads
  int b = t >> 8, j = (t & 255) << 2;
  float4 v = *(const float4*)(s + (size_t)b * 1024 + j);
  *(ushort4*)(d + (size_t)b * dld + j) = make_ushort4(f2bf(v.x), f2bf(v.y), f2bf(v.z), f2bf(v.w));
}

// input_t: convert into rcombined col 0..1023 AND accumulate var1 sums
__global__ void conv_var(const float* __restrict__ s, u16* __restrict__ d, float* __restrict__ sums) {
  int t = blockIdx.x * blockDim.x + threadIdx.x;  // 524288 threads
  int b = t >> 8, j = (t & 255) << 2;
  float4 v = *(const float4*)(s + (size_t)b * 1024 + j);
  *(ushort4*)(d + (size_t)b * 3072 + j) = make_ushort4(f2bf(v.x), f2bf(v.y), f2bf(v.z), f2bf(v.w));
  float ls = v.x + v.y + v.z + v.w;
  float lq = v.x * v.x + v.y * v.y + v.z * v.z + v.w * v.w;
#pragma unroll
  for (int off = 32; off; off >>= 1) { ls += __shfl_down(ls, off); lq += __shfl_down(lq, off); }
  if ((threadIdx.x & 63) == 0) { atomicAdd(&sums[0], ls); atomicAdd(&sums[1], lq); }
}

// AW = A_list * gc_W elementwise, to bf16
__global__ void make_AW(const float* __restrict__ a, const float* __restrict__ w,
                        u16* __restrict__ d, long n4) {
  long stride = (long)gridDim.x * blockDim.x;
  for (long i = blockIdx.x * (long)blockDim.x + threadIdx.x; i < n4; i += stride) {
    float4 va = *(const float4*)(a + i * 4);
    float4 vw = *(const float4*)(w + i * 4);
    *(ushort4*)(d + i * 4) = make_ushort4(f2bf(va.x * vw.x), f2bf(va.y * vw.y),
                                          f2bf(va.z * vw.z), f2bf(va.w * vw.w));
  }
}

// concat 4 bias vectors [1024] -> [4096]
__global__ void cat4(const float* __restrict__ a, const float* __restrict__ b,
                     const float* __restrict__ c, const float* __restrict__ d,
                     float* __restrict__ o) {
  int i = blockIdx.x * blockDim.x + threadIdx.x;  // 4096 threads
  const float* s = (i < 1024) ? a : (i < 2048) ? b : (i < 3072) ? c : d;
  o[i] = s[i & 1023];
}

// nvec[m] = sum_n A3[m][n] * Nw[n]
__global__ void nvec_kernel(const float* __restrict__ A3, const float* __restrict__ Nw,
                            float* __restrict__ nvec) {
  int m = blockIdx.x, t = threadIdx.x;
  float s = 0.f;
  for (int c = t; c < 1024; c += 256) s += A3[(size_t)m * 1024 + c] * Nw[c];
  __shared__ float red[4];
#pragma unroll
  for (int off = 32; off; off >>= 1) s += __shfl_down(s, off);
  if ((t & 63) == 0) red[t >> 6] = s;
  __syncthreads();
  if (t == 0) nvec[m] = red[0] + red[1] + red[2] + red[3];
}

// ---------------------------------------------------------------- GEMM (C = A @ W^T, bf16 MFMA)
// A: [M][K] bf16 (lda), W: [Ncols][K] bf16 (ldw). Block tile 128x128, BK=64.
// 256 threads = 4 waves in 2x2, each wave 64x64 via 4x4 of 16x16x32 MFMA.
// MODE 0: gc epilogue (fp32 out + bf16 copy + var2 sums). MODE 1: bias+activation.
template <int MODE>
__launch_bounds__(256)
__global__ void gemm_bt(const u16* __restrict__ A, int lda,
                        const u16* __restrict__ W, int ldw, int K,
                        float* __restrict__ out0, int ld0,
                        u16* __restrict__ outb, int ldb,
                        const float* __restrict__ bias,
                        float* __restrict__ sums) {
  __shared__ u16 lA[128 * 64];
  __shared__ u16 lB[128 * 64];
  const int tid = threadIdx.x;
  const int w = tid >> 6, l = tid & 63;
  const int bm = blockIdx.y << 7, bn = blockIdx.x << 7;
  const int waveM = ((w >> 1) & 1) << 6, waveN = (w & 1) << 6;
  const int quad = l >> 4, r16 = l & 15;

  // staging: each wave loads 32 rows of A-tile and 32 rows of B-tile, 4 issues of 8 rows
  // LDS dest = wave-uniform base + lane*16B; XOR-swizzle the fetched 16B chunk by row&7
  const int srow = l >> 3;            // row within 8-row chunk
  const int schunk = (l & 7) ^ srow;  // which global 16B chunk this lane fetches
  const u16* gA = A + (size_t)(bm + w * 32 + srow) * lda + schunk * 8;
  const u16* gB = W + (size_t)(bn + w * 32 + srow) * ldw + schunk * 8;
  u16* sA = lA + (w * 32) * 64;
  u16* sB = lB + (w * 32) * 64;

  f32x4 acc[4][4] = {};

  for (int k0 = 0; k0 < K; k0 += 64) {
#pragma unroll
    for (int i = 0; i < 4; i++) {
      glds16(gA + (size_t)(i * 8) * lda + k0, sA + i * 8 * 64);
      glds16(gB + (size_t)(i * 8) * ldw + k0, sB + i * 8 * 64);
    }
    __syncthreads();
#pragma unroll
    for (int ks = 0; ks < 2; ks++) {
      bf16x8 av[4], bv[4];
#pragma unroll
      for (int mi = 0; mi < 4; mi++) {
        int row = waveM + mi * 16 + r16;
        int ch = (ks * 4 + quad) ^ (r16 & 7);
        av[mi] = *(const bf16x8*)(lA + row * 64 + ch * 8);
      }
#pragma unroll
      for (int ni = 0; ni < 4; ni++) {
        int row = waveN + ni * 16 + r16;
        int ch = (ks * 4 + quad) ^ (r16 & 7);
        bv[ni] = *(const bf16x8*)(lB + row * 64 + ch * 8);
      }
#pragma unroll
      for (int mi = 0; mi < 4; mi++)
#pragma unroll
        for (int ni = 0; ni < 4; ni++)
          acc[mi][ni] = __builtin_amdgcn_mfma_f32_16x16x32_bf16(av[mi], bv[ni], acc[mi][ni], 0, 0, 0);
    }
    __syncthreads();
  }

  // C/D layout: col = lane&15, row = (lane>>4)*4 + reg
  if constexpr (MODE == 0) {
    float ls = 0.f, lq = 0.f;
#pragma unroll
    for (int mi = 0; mi < 4; mi++)
#pragma unroll
      for (int ni = 0; ni < 4; ni++) {
        int col = bn + waveN + ni * 16 + r16;
#pragma unroll
        for (int e = 0; e < 4; e++) {
          int row = bm + waveM + mi * 16 + quad * 4 + e;
          float v = acc[mi][ni][e];
          out0[(size_t)row * ld0 + col] = v;
          outb[(size_t)row * ldb + col] = f2bf(v);
          ls += v;
          lq += v * v;
        }
      }
#pragma unroll
    for (int off = 32; off; off >>= 1) { ls += __shfl_down(ls, off); lq += __shfl_down(lq, off); }
    if (l == 0) { atomicAdd(&sums[2], ls); atomicAdd(&sums[3], lq); }
  } else {
#pragma unroll
    for (int mi = 0; mi < 4; mi++)
#pragma unroll
      for (int ni = 0; ni < 4; ni++) {
        int col = bn + waveN + ni * 16 + r16;
        float bb = bias[col];
        bool sig = col < 3072;  // gates f,i,o sigmoid; gate C tanh
#pragma unroll
        for (int e = 0; e < 4; e++) {
          int row = bm + waveM + mi * 16 + quad * 4 + e;
          float v = acc[mi][ni][e] + bb;
          v = sig ? (1.f / (1.f + __expf(-v))) : tanhf(v);
          out0[(size_t)row * ld0 + col] = v;
        }
      }
  }
}

// ---------------------------------------------------------------- epilogue kernels

__global__ void cell_kernel(const float* __restrict__ g, const float* __restrict__ CS,
                            const float* __restrict__ nvec, float* __restrict__ CellOut,
                            float* __restrict__ Hid) {
  int t = blockIdx.x * blockDim.x + threadIdx.x;  // 524288
  int b = t >> 8, j = (t & 255) << 2;
  const float* gr = g + (size_t)b * 4096;
  float4 f = *(const float4*)(gr + j);
  float4 ii = *(const float4*)(gr + 1024 + j);
  float4 o = *(const float4*)(gr + 2048 + j);
  float4 C = *(const float4*)(gr + 3072 + j);
  float4 cs = *(const float4*)(CS + (size_t)b * 1024 + j);
  float4 nv = *(const float4*)(nvec + j);
  float4 cell, hid;
  cell.x = f.x * (cs.x * nv.x) + ii.x * C.x; hid.x = o.x * tanhf(cell.x);
  cell.y = f.y * (cs.y * nv.y) + ii.y * C.y; hid.y = o.y * tanhf(cell.y);
  cell.z = f.z * (cs.z * nv.z) + ii.z * C.z; hid.z = o.z * tanhf(cell.z);
  cell.w = f.w * (cs.w * nv.w) + ii.w * C.w; hid.w = o.w * tanhf(cell.w);
  *(float4*)(CellOut + (size_t)b * 1024 + j) = cell;
  *(float4*)(Hid + (size_t)b * 1024 + j) = hid;
}

__global__ void rcell_kernel(const float* __restrict__ g, const float* __restrict__ rCS,
                             float* __restrict__ rCellOut, float* __restrict__ rHid) {
  int t = blockIdx.x * blockDim.x + threadIdx.x;
  int b = t >> 8, j = (t & 255) << 2;
  const float* gr = g + (size_t)b * 4096;
  float4 f = *(const float4*)(gr + j);
  float4 ii = *(const float4*)(gr + 1024 + j);
  float4 o = *(const float4*)(gr + 2048 + j);
  float4 C = *(const float4*)(gr + 3072 + j);
  float4 cs = *(const float4*)(rCS + (size_t)b * 1024 + j);
  float4 cell, hid;
  cell.x = f.x * cs.x + ii.x * C.x; hid.x = o.x * tanhf(cell.x);
  cell.y = f.y * cs.y + ii.y * C.y; hid.y = o.y * tanhf(cell.y);
  cell.z = f.z * cs.z + ii.z * C.z; hid.z = o.z * tanhf(cell.z);
  cell.w = f.w * cs.w + ii.w * C.w; hid.w = o.w * tanhf(cell.w);
  *(float4*)(rCellOut + (size_t)b * 1024 + j) = cell;
  *(float4*)(rHid + (size_t)b * 1024 + j) = hid;
}

__global__ void final_kernel(const float* __restrict__ Hid, const float* __restrict__ rHid,
                             const float* __restrict__ sums, const float* __restrict__ cp,
                             float* __restrict__ Hout, float* __restrict__ predOut,
                             float* __restrict__ rHout) {
  const float n1 = 2097152.f, n2 = 6291456.f;
  float var1 = (sums[1] - sums[0] * sums[0] / n1) / (n1 - 1.f);
  float var2 = (sums[3] - sums[2] * sums[2] / n2) / (n2 - 1.f);
  float c = cp[0];
  float inv = 1.f / (var1 + var2 * c);
  float s1 = var1 * c, s2 = var2;
  int t = blockIdx.x * blockDim.x + threadIdx.x;
  size_t i = (size_t)t << 2;
  float4 H = *(const float4*)(Hid + i);
  float4 R = *(const float4*)(rHid + i);
  float4 p, ho, rho;
  p.x = (H.x * s1 + R.x * s2) * inv; ho.x = H.x - p.x; rho.x = R.x - p.x;
  p.y = (H.y * s1 + R.y * s2) * inv; ho.y = H.y - p.y; rho.y = R.y - p.y;
  p.z = (H.z * s1 + R.z * s2) * inv; ho.z = H.z - p.z; rho.z = R.z - p.z;
  p.w = (H.w * s1 + R.w * s2) * inv; ho.w = H.w - p.w; rho.w = R.w - p.w;
  *(float4*)(predOut + i) = p;
  *(float4*)(Hout + i) = ho;
  *(float4*)(rHout + i) = rho;
}

// ---------------------------------------------------------------- launch

extern "C" void kernel_launch(void* const* d_in, const int* in_sizes, int n_in,
                              void* d_out, int out_size, void* d_ws, size_t ws_size,
                              hipStream_t stream) {
  const float* input   = (const float*)d_in[0];
  const float* input_t = (const float*)d_in[1];
  const float* HS      = (const float*)d_in[2];
  const float* CS      = (const float*)d_in[3];
  const float* rHS     = (const float*)d_in[4];
  const float* rCS     = (const float*)d_in[5];
  const float* pred    = (const float*)d_in[6];
  const float* A_list  = (const float*)d_in[7];
  const float* gc_W    = (const float*)d_in[8];
  const float* fl_W  = (const float*)d_in[9];  const float* fl_b  = (const float*)d_in[10];
  const float* il_W  = (const float*)d_in[11]; const float* il_b  = (const float*)d_in[12];
  const float* ol_W  = (const float*)d_in[13]; const float* ol_b  = (const float*)d_in[14];
  const float* Cl_W  = (const float*)d_in[15]; const float* Cl_b  = (const float*)d_in[16];
  const float* Nw    = (const float*)d_in[17];
  const float* rfl_W = (const float*)d_in[18]; const float* rfl_b = (const float*)d_in[19];
  const float* ril_W = (const float*)d_in[20]; const float* ril_b = (const float*)d_in[21];
  const float* rol_W = (const float*)d_in[22]; const float* rol_b = (const float*)d_in[23];
  const float* rCl_W = (const float*)d_in[24]; const float* rCl_b = (const float*)d_in[25];
  const float* cp    = (const float*)d_in[26];

  float* out      = (float*)d_out;
  float* Hout     = out;                // [2048][1024]
  float* CellOut  = out + 2097152;      // [2048][1024]
  float* gcOut    = out + 4194304;      // [2048][3072]
  float* rHout    = out + 10485760;     // [2048][1024]
  float* rCellOut = out + 12582912;     // [2048][1024]
  float* predOut  = out + 14680064;     // [2048][1024]

  // workspace carve-up (~150 MB)
  char* ws = (char*)d_ws;
  size_t off = 0;
  auto alloc = [&](size_t bytes) -> void* {
    void* p = ws + off;
    off = (off + bytes + 255) & ~(size_t)255;
    return p;
  };
  float* sums   = (float*)alloc(16);                           // var1 sum/sq, var2 sum/sq
  float* nvec   = (float*)alloc(1024 * 4);
  float* bias_g = (float*)alloc(4096 * 4);
  float* bias_r = (float*)alloc(4096 * 4);
  u16* comb  = (u16*)alloc((size_t)2048 * 5120 * 2);           // [gc | HS | pred] bf16
  u16* rcomb = (u16*)alloc((size_t)2048 * 3072 * 2);           // [input_t | rHS | pred] bf16
  u16* AW    = (u16*)alloc((size_t)3 * 1024 * 1024 * 2);       // masked gc weights bf16
  u16* gW    = (u16*)alloc((size_t)4096 * 5120 * 2);           // gate weights bf16
  u16* rW    = (u16*)alloc((size_t)4096 * 3072 * 2);           // r-gate weights bf16
  float* gates = (float*)alloc((size_t)2048 * 4096 * 4);       // gate acts (reused for r-gates)
  float* Hid   = (float*)alloc((size_t)2048 * 1024 * 4);
  float* rHid  = (float*)alloc((size_t)2048 * 1024 * 4);
  // bA (input bf16) aliases the gates buffer: dead before GEMM2 writes gates
  u16* bA = (u16*)gates;

  zero4_kernel<<<1, 64, 0, stream>>>(sums);

  conv_cat<<<2048, 256, 0, stream>>>(input, bA, 2048L * 1024 / 4);
  conv_var<<<2048, 256, 0, stream>>>(input_t, rcomb, sums);
  conv_strided<<<2048, 256, 0, stream>>>(HS, comb + 3072, 5120);
  conv_strided<<<2048, 256, 0, stream>>>(pred, comb + 4096, 5120);
  conv_strided<<<2048, 256, 0, stream>>>(rHS, rcomb + 1024, 3072);
  conv_strided<<<2048, 256, 0, stream>>>(pred, rcomb + 2048, 3072);
  make_AW<<<2048, 256, 0, stream>>>(A_list, gc_W, AW, 3L * 1024 * 1024 / 4);
  conv_cat<<<2048, 256, 0, stream>>>(fl_W, gW + 0L * 1024 * 5120, 1024L * 5120 / 4);
  conv_cat<<<2048, 256, 0, stream>>>(il_W, gW + 1L * 1024 * 5120, 1024L * 5120 / 4);
  conv_cat<<<2048, 256, 0, stream>>>(ol_W, gW + 2L * 1024 * 5120, 1024L * 5120 / 4);
  conv_cat<<<2048, 256, 0, stream>>>(Cl_W, gW + 3L * 1024 * 5120, 1024L * 5120 / 4);
  conv_cat<<<2048, 256, 0, stream>>>(rfl_W, rW + 0L * 1024 * 3072, 1024L * 3072 / 4);
  conv_cat<<<2048, 256, 0, stream>>>(ril_W, rW + 1L * 1024 * 3072, 1024L * 3072 / 4);
  conv_cat<<<2048, 256, 0, stream>>>(rol_W, rW + 2L * 1024 * 3072, 1024L * 3072 / 4);
  conv_cat<<<2048, 256, 0, stream>>>(rCl_W, rW + 3L * 1024 * 3072, 1024L * 3072 / 4);
  cat4<<<16, 256, 0, stream>>>(fl_b, il_b, ol_b, Cl_b, bias_g);
  cat4<<<16, 256, 0, stream>>>(rfl_b, ril_b, rol_b, rCl_b, bias_r);
  nvec_kernel<<<1024, 256, 0, stream>>>(A_list + 2L * 1024 * 1024, Nw, nvec);

  // GEMM1: gc = input @ AW^T   [2048 x 3072], K=1024
  gemm_bt<0><<<dim3(24, 16), 256, 0, stream>>>(bA, 1024, AW, 1024, 1024,
                                               gcOut, 3072, comb, 5120, nullptr, sums);
  // GEMM2: gates = combined @ gW^T  [2048 x 4096], K=5120 (+bias, sigmoid/tanh)
  gemm_bt<1><<<dim3(32, 16), 256, 0, stream>>>(comb, 5120, gW, 5120, 5120,
                                               gates, 4096, nullptr, 0, bias_g, nullptr);
  cell_kernel<<<2048, 256, 0, stream>>>(gates, CS, nvec, CellOut, Hid);
  // GEMM3: rgates = rcombined @ rW^T  [2048 x 4096], K=3072
  gemm_bt<1><<<dim3(32, 16), 256, 0, stream>>>(rcomb, 3072, rW, 3072, 3072,
                                               gates, 4096, nullptr, 0, bias_r, nullptr);
  rcell_kernel<<<2048, 256, 0, stream>>>(gates, rCS, rCellOut, rHid);
  final_kernel<<<2048, 256, 0, stream>>>(Hid, rHid, sums, cp, Hout, predOut, rHout);

  (void)in_sizes; (void)n_in; (void)out_size; (void)ws_size;
}

// Round 2
// 557.028 us; speedup vs baseline: 1.4250x; 1.4250x over previous
//
#include <hip/hip_runtime.h>
#include <cstdint>
#include <cstddef>

typedef unsigned short u16;
typedef __attribute__((ext_vector_type(8))) __bf16 bf16x8;
typedef __attribute__((ext_vector_type(4))) float f32x4;

#define DEV __device__ __forceinline__

DEV u16 f2bf(float f) {
  unsigned u = __float_as_uint(f);
  return (u16)((u + 0x7FFFu + ((u >> 16) & 1u)) >> 16);
}

DEV void glds16(const void* g, void* l) {
  __builtin_amdgcn_global_load_lds((const __attribute__((address_space(1))) void*)g,
                                   (__attribute__((address_space(3))) void*)l,
                                   16, 0, 0);
}

// ---------------------------------------------------------------- prep kernels

// contiguous fp32 -> bf16 convert, vectorized x4, grid-stride
__global__ void conv_cat(const float* __restrict__ s, u16* __restrict__ d, long n4) {
  long stride = (long)gridDim.x * blockDim.x;
  for (long i = blockIdx.x * (long)blockDim.x + threadIdx.x; i < n4; i += stride) {
    float4 v = *(const float4*)(s + i * 4);
    *(ushort4*)(d + i * 4) = make_ushort4(f2bf(v.x), f2bf(v.y), f2bf(v.z), f2bf(v.w));
  }
}

// [2048][1024] fp32 -> bf16 into dst with leading dim dld (for concat buffers)
__global__ void conv_strided(const float* __restrict__ s, u16* __restrict__ d, int dld) {
  int t = blockIdx.x * blockDim.x + threadIdx.x;  // 524288 threads
  int b = t >> 8, j = (t & 255) << 2;
  float4 v = *(const float4*)(s + (size_t)b * 1024 + j);
  *(ushort4*)(d + (size_t)b * dld + j) = make_ushort4(f2bf(v.x), f2bf(v.y), f2bf(v.z), f2bf(v.w));
}

// input_t: convert into rcombined col 0..1023 AND write per-block var1 partial sums
__global__ void conv_var(const float* __restrict__ s, u16* __restrict__ d,
                         float* __restrict__ partials) {
  int t = blockIdx.x * blockDim.x + threadIdx.x;  // 524288 threads
  int b = t >> 8, j = (t & 255) << 2;
  float4 v = *(const float4*)(s + (size_t)b * 1024 + j);
  *(ushort4*)(d + (size_t)b * 3072 + j) = make_ushort4(f2bf(v.x), f2bf(v.y), f2bf(v.z), f2bf(v.w));
  float ls = v.x + v.y + v.z + v.w;
  float lq = v.x * v.x + v.y * v.y + v.z * v.z + v.w * v.w;
#pragma unroll
  for (int off = 32; off; off >>= 1) { ls += __shfl_down(ls, off); lq += __shfl_down(lq, off); }
  __shared__ float red[8];
  if ((threadIdx.x & 63) == 0) {
    int w = threadIdx.x >> 6;
    red[w] = ls; red[4 + w] = lq;
  }
  __syncthreads();
  if (threadIdx.x == 0) {
    partials[(size_t)blockIdx.x * 2]     = red[0] + red[1] + red[2] + red[3];
    partials[(size_t)blockIdx.x * 2 + 1] = red[4] + red[5] + red[6] + red[7];
  }
}

// AW = A_list * gc_W elementwise, to bf16
__global__ void make_AW(const float* __restrict__ a, const float* __restrict__ w,
                        u16* __restrict__ d, long n4) {
  long stride = (long)gridDim.x * blockDim.x;
  for (long i = blockIdx.x * (long)blockDim.x + threadIdx.x; i < n4; i += stride) {
    float4 va = *(const float4*)(a + i * 4);
    float4 vw = *(const float4*)(w + i * 4);
    *(ushort4*)(d + i * 4) = make_ushort4(f2bf(va.x * vw.x), f2bf(va.y * vw.y),
                                          f2bf(va.z * vw.z), f2bf(va.w * vw.w));
  }
}

// concat 4 bias vectors [1024] -> [4096]
__global__ void cat4(const float* __restrict__ a, const float* __restrict__ b,
                     const float* __restrict__ c, const float* __restrict__ d,
                     float* __restrict__ o) {
  int i = blockIdx.x * blockDim.x + threadIdx.x;  // 4096 threads
  const float* s = (i < 1024) ? a : (i < 2048) ? b : (i < 3072) ? c : d;
  o[i] = s[i & 1023];
}

// nvec[m] = sum_n A3[m][n] * Nw[n]
__global__ void nvec_kernel(const float* __restrict__ A3, const float* __restrict__ Nw,
                            float* __restrict__ nvec) {
  int m = blockIdx.x, t = threadIdx.x;
  float s = 0.f;
  for (int c = t; c < 1024; c += 256) s += A3[(size_t)m * 1024 + c] * Nw[c];
  __shared__ float red[4];
#pragma unroll
  for (int off = 32; off; off >>= 1) s += __shfl_down(s, off);
  if ((t & 63) == 0) red[t >> 6] = s;
  __syncthreads();
  if (t == 0) nvec[m] = red[0] + red[1] + red[2] + red[3];
}

// fold per-block partials into sums[0..3] — single block, no atomics anywhere
__global__ void reduce_sums(const float* __restrict__ p1, int n1,
                            const float* __restrict__ p2, int n2,
                            float* __restrict__ sums) {
  float a = 0.f, b = 0.f, c = 0.f, d = 0.f;
  for (int i = threadIdx.x; i < n1; i += 256) { a += p1[2 * i]; b += p1[2 * i + 1]; }
  for (int i = threadIdx.x; i < n2; i += 256) { c += p2[2 * i]; d += p2[2 * i + 1]; }
#pragma unroll
  for (int off = 32; off; off >>= 1) {
    a += __shfl_down(a, off); b += __shfl_down(b, off);
    c += __shfl_down(c, off); d += __shfl_down(d, off);
  }
  __shared__ float red[16];
  if ((threadIdx.x & 63) == 0) {
    int w = threadIdx.x >> 6;
    red[w] = a; red[4 + w] = b; red[8 + w] = c; red[12 + w] = d;
  }
  __syncthreads();
  if (threadIdx.x == 0) {
    sums[0] = red[0] + red[1] + red[2] + red[3];
    sums[1] = red[4] + red[5] + red[6] + red[7];
    sums[2] = red[8] + red[9] + red[10] + red[11];
    sums[3] = red[12] + red[13] + red[14] + red[15];
  }
}

// ---------------------------------------------------------------- GEMM (C = A @ W^T, bf16 MFMA)
// A: [M][K] bf16 (lda), W: [Ncols][K] bf16 (ldw). Block tile 128x128, BK=64.
// 256 threads = 4 waves in 2x2, each wave 64x64 via 4x4 of 16x16x32 MFMA.
// MODE 0: gc epilogue (fp32 out + bf16 copy + per-block var2 partials). MODE 1: bias+activation.
template <int MODE>
__launch_bounds__(256)
__global__ void gemm_bt(const u16* __restrict__ A, int lda,
                        const u16* __restrict__ W, int ldw, int K,
                        float* __restrict__ out0, int ld0,
                        u16* __restrict__ outb, int ldb,
                        const float* __restrict__ bias,
                        float* __restrict__ partials) {
  __shared__ u16 lA[128 * 64];
  __shared__ u16 lB[128 * 64];
  const int tid = threadIdx.x;
  const int w = tid >> 6, l = tid & 63;
  const int bm = blockIdx.y << 7, bn = blockIdx.x << 7;
  const int waveM = ((w >> 1) & 1) << 6, waveN = (w & 1) << 6;
  const int quad = l >> 4, r16 = l & 15;

  // staging: each wave loads 32 rows of A-tile and 32 rows of B-tile, 4 issues of 8 rows
  // LDS dest = wave-uniform base + lane*16B; XOR-swizzle the fetched 16B chunk by row&7
  const int srow = l >> 3;            // row within 8-row chunk
  const int schunk = (l & 7) ^ srow;  // which global 16B chunk this lane fetches
  const u16* gA = A + (size_t)(bm + w * 32 + srow) * lda + schunk * 8;
  const u16* gB = W + (size_t)(bn + w * 32 + srow) * ldw + schunk * 8;
  u16* sA = lA + (w * 32) * 64;
  u16* sB = lB + (w * 32) * 64;

  f32x4 acc[4][4] = {};

  for (int k0 = 0; k0 < K; k0 += 64) {
#pragma unroll
    for (int i = 0; i < 4; i++) {
      glds16(gA + (size_t)(i * 8) * lda + k0, sA + i * 8 * 64);
      glds16(gB + (size_t)(i * 8) * ldw + k0, sB + i * 8 * 64);
    }
    __syncthreads();
#pragma unroll
    for (int ks = 0; ks < 2; ks++) {
      bf16x8 av[4], bv[4];
#pragma unroll
      for (int mi = 0; mi < 4; mi++) {
        int row = waveM + mi * 16 + r16;
        int ch = (ks * 4 + quad) ^ (r16 & 7);
        av[mi] = *(const bf16x8*)(lA + row * 64 + ch * 8);
      }
#pragma unroll
      for (int ni = 0; ni < 4; ni++) {
        int row = waveN + ni * 16 + r16;
        int ch = (ks * 4 + quad) ^ (r16 & 7);
        bv[ni] = *(const bf16x8*)(lB + row * 64 + ch * 8);
      }
#pragma unroll
      for (int mi = 0; mi < 4; mi++)
#pragma unroll
        for (int ni = 0; ni < 4; ni++)
          acc[mi][ni] = __builtin_amdgcn_mfma_f32_16x16x32_bf16(av[mi], bv[ni], acc[mi][ni], 0, 0, 0);
    }
    __syncthreads();
  }

  // C/D layout: col = lane&15, row = (lane>>4)*4 + reg
  if constexpr (MODE == 0) {
    float ls = 0.f, lq = 0.f;
#pragma unroll
    for (int mi = 0; mi < 4; mi++)
#pragma unroll
      for (int ni = 0; ni < 4; ni++) {
        int col = bn + waveN + ni * 16 + r16;
#pragma unroll
        for (int e = 0; e < 4; e++) {
          int row = bm + waveM + mi * 16 + quad * 4 + e;
          float v = acc[mi][ni][e];
          out0[(size_t)row * ld0 + col] = v;
          outb[(size_t)row * ldb + col] = f2bf(v);
          ls += v;
          lq += v * v;
        }
      }
#pragma unroll
    for (int off = 32; off; off >>= 1) { ls += __shfl_down(ls, off); lq += __shfl_down(lq, off); }
    __shared__ float red[8];
    if (l == 0) { red[w] = ls; red[4 + w] = lq; }
    __syncthreads();
    if (tid == 0) {
      int bidx = blockIdx.y * gridDim.x + blockIdx.x;
      partials[(size_t)bidx * 2]     = red[0] + red[1] + red[2] + red[3];
      partials[(size_t)bidx * 2 + 1] = red[4] + red[5] + red[6] + red[7];
    }
  } else {
#pragma unroll
    for (int mi = 0; mi < 4; mi++)
#pragma unroll
      for (int ni = 0; ni < 4; ni++) {
        int col = bn + waveN + ni * 16 + r16;
        float bb = bias[col];
        bool sig = col < 3072;  // gates f,i,o sigmoid; gate C tanh
#pragma unroll
        for (int e = 0; e < 4; e++) {
          int row = bm + waveM + mi * 16 + quad * 4 + e;
          float v = acc[mi][ni][e] + bb;
          v = sig ? (1.f / (1.f + __expf(-v))) : tanhf(v);
          out0[(size_t)row * ld0 + col] = v;
        }
      }
  }
}

// ---------------------------------------------------------------- epilogue kernels

__global__ void cell_kernel(const float* __restrict__ g, const float* __restrict__ CS,
                            const float* __restrict__ nvec, float* __restrict__ CellOut,
                            float* __restrict__ Hid) {
  int t = blockIdx.x * blockDim.x + threadIdx.x;  // 524288
  int b = t >> 8, j = (t & 255) << 2;
  const float* gr = g + (size_t)b * 4096;
  float4 f = *(const float4*)(gr + j);
  float4 ii = *(const float4*)(gr + 1024 + j);
  float4 o = *(const float4*)(gr + 2048 + j);
  float4 C = *(const float4*)(gr + 3072 + j);
  float4 cs = *(const float4*)(CS + (size_t)b * 1024 + j);
  float4 nv = *(const float4*)(nvec + j);
  float4 cell, hid;
  cell.x = f.x * (cs.x * nv.x) + ii.x * C.x; hid.x = o.x * tanhf(cell.x);
  cell.y = f.y * (cs.y * nv.y) + ii.y * C.y; hid.y = o.y * tanhf(cell.y);
  cell.z = f.z * (cs.z * nv.z) + ii.z * C.z; hid.z = o.z * tanhf(cell.z);
  cell.w = f.w * (cs.w * nv.w) + ii.w * C.w; hid.w = o.w * tanhf(cell.w);
  *(float4*)(CellOut + (size_t)b * 1024 + j) = cell;
  *(float4*)(Hid + (size_t)b * 1024 + j) = hid;
}

__global__ void rcell_kernel(const float* __restrict__ g, const float* __restrict__ rCS,
                             float* __restrict__ rCellOut, float* __restrict__ rHid) {
  int t = blockIdx.x * blockDim.x + threadIdx.x;
  int b = t >> 8, j = (t & 255) << 2;
  const float* gr = g + (size_t)b * 4096;
  float4 f = *(const float4*)(gr + j);
  float4 ii = *(const float4*)(gr + 1024 + j);
  float4 o = *(const float4*)(gr + 2048 + j);
  float4 C = *(const float4*)(gr + 3072 + j);
  float4 cs = *(const float4*)(rCS + (size_t)b * 1024 + j);
  float4 cell, hid;
  cell.x = f.x * cs.x + ii.x * C.x; hid.x = o.x * tanhf(cell.x);
  cell.y = f.y * cs.y + ii.y * C.y; hid.y = o.y * tanhf(cell.y);
  cell.z = f.z * cs.z + ii.z * C.z; hid.z = o.z * tanhf(cell.z);
  cell.w = f.w * cs.w + ii.w * C.w; hid.w = o.w * tanhf(cell.w);
  *(float4*)(rCellOut + (size_t)b * 1024 + j) = cell;
  *(float4*)(rHid + (size_t)b * 1024 + j) = hid;
}

__global__ void final_kernel(const float* __restrict__ Hid, const float* __restrict__ rHid,
                             const float* __restrict__ sums, const float* __restrict__ cp,
                             float* __restrict__ Hout, float* __restrict__ predOut,
                             float* __restrict__ rHout) {
  const float n1 = 2097152.f, n2 = 6291456.f;
  float var1 = (sums[1] - sums[0] * sums[0] / n1) / (n1 - 1.f);
  float var2 = (sums[3] - sums[2] * sums[2] / n2) / (n2 - 1.f);
  float c = cp[0];
  float inv = 1.f / (var1 + var2 * c);
  float s1 = var1 * c, s2 = var2;
  int t = blockIdx.x * blockDim.x + threadIdx.x;
  size_t i = (size_t)t << 2;
  float4 H = *(const float4*)(Hid + i);
  float4 R = *(const float4*)(rHid + i);
  float4 p, ho, rho;
  p.x = (H.x * s1 + R.x * s2) * inv; ho.x = H.x - p.x; rho.x = R.x - p.x;
  p.y = (H.y * s1 + R.y * s2) * inv; ho.y = H.y - p.y; rho.y = R.y - p.y;
  p.z = (H.z * s1 + R.z * s2) * inv; ho.z = H.z - p.z; rho.z = R.z - p.z;
  p.w = (H.w * s1 + R.w * s2) * inv; ho.w = H.w - p.w; rho.w = R.w - p.w;
  *(float4*)(predOut + i) = p;
  *(float4*)(Hout + i) = ho;
  *(float4*)(rHout + i) = rho;
}

// ---------------------------------------------------------------- launch

extern "C" void kernel_launch(void* const* d_in, const int* in_sizes, int n_in,
                              void* d_out, int out_size, void* d_ws, size_t ws_size,
                              hipStream_t stream) {
  const float* input   = (const float*)d_in[0];
  const float* input_t = (const float*)d_in[1];
  const float* HS      = (const float*)d_in[2];
  const float* CS      = (const float*)d_in[3];
  const float* rHS     = (const float*)d_in[4];
  const float* rCS     = (const float*)d_in[5];
  const float* pred    = (const float*)d_in[6];
  const float* A_list  = (const float*)d_in[7];
  const float* gc_W    = (const float*)d_in[8];
  const float* fl_W  = (const float*)d_in[9];  const float* fl_b  = (const float*)d_in[10];
  const float* il_W  = (const float*)d_in[11]; const float* il_b  = (const float*)d_in[12];
  const float* ol_W  = (const float*)d_in[13]; const float* ol_b  = (const float*)d_in[14];
  const float* Cl_W  = (const float*)d_in[15]; const float* Cl_b  = (const float*)d_in[16];
  const float* Nw    = (const float*)d_in[17];
  const float* rfl_W = (const float*)d_in[18]; const float* rfl_b = (const float*)d_in[19];
  const float* ril_W = (const float*)d_in[20]; const float* ril_b = (const float*)d_in[21];
  const float* rol_W = (const float*)d_in[22]; const float* rol_b = (const float*)d_in[23];
  const float* rCl_W = (const float*)d_in[24]; const float* rCl_b = (const float*)d_in[25];
  const float* cp    = (const float*)d_in[26];

  float* out      = (float*)d_out;
  float* Hout     = out;                // [2048][1024]
  float* CellOut  = out + 2097152;      // [2048][1024]
  float* gcOut    = out + 4194304;      // [2048][3072]
  float* rHout    = out + 10485760;     // [2048][1024]
  float* rCellOut = out + 12582912;     // [2048][1024]
  float* predOut  = out + 14680064;     // [2048][1024]

  // workspace carve-up (~150 MB)
  char* ws = (char*)d_ws;
  size_t off = 0;
  auto alloc = [&](size_t bytes) -> void* {
    void* p = ws + off;
    off = (off + bytes + 255) & ~(size_t)255;
    return p;
  };
  float* sums   = (float*)alloc(16);                           // var1 sum/sq, var2 sum/sq
  float* part1  = (float*)alloc(2048 * 2 * 4);                 // conv_var block partials
  float* part2  = (float*)alloc(384 * 2 * 4);                  // gemm1 block partials
  float* nvec   = (float*)alloc(1024 * 4);
  float* bias_g = (float*)alloc(4096 * 4);
  float* bias_r = (float*)alloc(4096 * 4);
  u16* comb  = (u16*)alloc((size_t)2048 * 5120 * 2);           // [gc | HS | pred] bf16
  u16* rcomb = (u16*)alloc((size_t)2048 * 3072 * 2);           // [input_t | rHS | pred] bf16
  u16* AW    = (u16*)alloc((size_t)3 * 1024 * 1024 * 2);       // masked gc weights bf16
  u16* gW    = (u16*)alloc((size_t)4096 * 5120 * 2);           // gate weights bf16
  u16* rW    = (u16*)alloc((size_t)4096 * 3072 * 2);           // r-gate weights bf16
  float* gates = (float*)alloc((size_t)2048 * 4096 * 4);       // gate acts (reused for r-gates)
  float* Hid   = (float*)alloc((size_t)2048 * 1024 * 4);
  float* rHid  = (float*)alloc((size_t)2048 * 1024 * 4);
  // bA (input bf16) aliases the gates buffer: dead before GEMM2 writes gates
  u16* bA = (u16*)gates;

  conv_cat<<<2048, 256, 0, stream>>>(input, bA, 2048L * 1024 / 4);
  conv_var<<<2048, 256, 0, stream>>>(input_t, rcomb, part1);
  conv_strided<<<2048, 256, 0, stream>>>(HS, comb + 3072, 5120);
  conv_strided<<<2048, 256, 0, stream>>>(pred, comb + 4096, 5120);
  conv_strided<<<2048, 256, 0, stream>>>(rHS, rcomb + 1024, 3072);
  conv_strided<<<2048, 256, 0, stream>>>(pred, rcomb + 2048, 3072);
  make_AW<<<2048, 256, 0, stream>>>(A_list, gc_W, AW, 3L * 1024 * 1024 / 4);
  conv_cat<<<2048, 256, 0, stream>>>(fl_W, gW + 0L * 1024 * 5120, 1024L * 5120 / 4);
  conv_cat<<<2048, 256, 0, stream>>>(il_W, gW + 1L * 1024 * 5120, 1024L * 5120 / 4);
  conv_cat<<<2048, 256, 0, stream>>>(ol_W, gW + 2L * 1024 * 5120, 1024L * 5120 / 4);
  conv_cat<<<2048, 256, 0, stream>>>(Cl_W, gW + 3L * 1024 * 5120, 1024L * 5120 / 4);
  conv_cat<<<2048, 256, 0, stream>>>(rfl_W, rW + 0L * 1024 * 3072, 1024L * 3072 / 4);
  conv_cat<<<2048, 256, 0, stream>>>(ril_W, rW + 1L * 1024 * 3072, 1024L * 3072 / 4);
  conv_cat<<<2048, 256, 0, stream>>>(rol_W, rW + 2L * 1024 * 3072, 1024L * 3072 / 4);
  conv_cat<<<2048, 256, 0, stream>>>(rCl_W, rW + 3L * 1024 * 3072, 1024L * 3072 / 4);
  cat4<<<16, 256, 0, stream>>>(fl_b, il_b, ol_b, Cl_b, bias_g);
  cat4<<<16, 256, 0, stream>>>(rfl_b, ril_b, rol_b, rCl_b, bias_r);
  nvec_kernel<<<1024, 256, 0, stream>>>(A_list + 2L * 1024 * 1024, Nw, nvec);

  // GEMM1: gc = input @ AW^T   [2048 x 3072], K=1024
  gemm_bt<0><<<dim3(24, 16), 256, 0, stream>>>(bA, 1024, AW, 1024, 1024,
                                               gcOut, 3072, comb, 5120, nullptr, part2);
  reduce_sums<<<1, 256, 0, stream>>>(part1, 2048, part2, 384, sums);
  // GEMM2: gates = combined @ gW^T  [2048 x 4096], K=5120 (+bias, sigmoid/tanh)
  gemm_bt<1><<<dim3(32, 16), 256, 0, stream>>>(comb, 5120, gW, 5120, 5120,
                                               gates, 4096, nullptr, 0, bias_g, nullptr);
  cell_kernel<<<2048, 256, 0, stream>>>(gates, CS, nvec, CellOut, Hid);
  // GEMM3: rgates = rcombined @ rW^T  [2048 x 4096], K=3072
  gemm_bt<1><<<dim3(32, 16), 256, 0, stream>>>(rcomb, 3072, rW, 3072, 3072,
                                               gates, 4096, nullptr, 0, bias_r, nullptr);
  rcell_kernel<<<2048, 256, 0, stream>>>(gates, rCS, rCellOut, rHid);
  final_kernel<<<2048, 256, 0, stream>>>(Hid, rHid, sums, cp, Hout, predOut, rHout);

  (void)in_sizes; (void)n_in; (void)out_size; (void)ws_size;
}

// Round 3
// 552.573 us; speedup vs baseline: 1.4365x; 1.0081x over previous
//
#include <hip/hip_runtime.h>
#include <cstdint>
#include <cstddef>

typedef unsigned short u16;
typedef __attribute__((ext_vector_type(8))) __bf16 bf16x8;
typedef __attribute__((ext_vector_type(4))) float f32x4;

#define DEV __device__ __forceinline__

DEV u16 f2bf(float f) {
  unsigned u = __float_as_uint(f);
  return (u16)((u + 0x7FFFu + ((u >> 16) & 1u)) >> 16);
}
DEV float bf2f(u16 b) { return __uint_as_float((unsigned)b << 16); }

DEV void glds16(const void* g, void* l) {
  __builtin_amdgcn_global_load_lds((const __attribute__((address_space(1))) void*)g,
                                   (__attribute__((address_space(3))) void*)l,
                                   16, 0, 0);
}

// ---------------------------------------------------------------- prep kernels

// contiguous fp32 -> bf16 convert, vectorized x4, grid-stride
__global__ void conv_cat(const float* __restrict__ s, u16* __restrict__ d, long n4) {
  long stride = (long)gridDim.x * blockDim.x;
  for (long i = blockIdx.x * (long)blockDim.x + threadIdx.x; i < n4; i += stride) {
    float4 v = *(const float4*)(s + i * 4);
    *(ushort4*)(d + i * 4) = make_ushort4(f2bf(v.x), f2bf(v.y), f2bf(v.z), f2bf(v.w));
  }
}

// 4 equal-size fp32 sources -> one concatenated bf16 dest. bps blocks per segment.
__global__ void wconv4(const float* __restrict__ s0, const float* __restrict__ s1,
                       const float* __restrict__ s2, const float* __restrict__ s3,
                       u16* __restrict__ d, long segn4, int bps) {
  int seg = blockIdx.x / bps;
  int tb = blockIdx.x - seg * bps;
  const float* s = (seg == 0) ? s0 : (seg == 1) ? s1 : (seg == 2) ? s2 : s3;
  u16* dd = d + (size_t)seg * segn4 * 4;
  long stride = (long)bps * blockDim.x;
  for (long i = (long)tb * blockDim.x + threadIdx.x; i < segn4; i += stride) {
    float4 v = *(const float4*)(s + i * 4);
    *(ushort4*)(dd + i * 4) = make_ushort4(f2bf(v.x), f2bf(v.y), f2bf(v.z), f2bf(v.w));
  }
}

// [2048][1024] fp32 -> bf16 into dst with leading dim dld (for concat buffers)
__global__ void conv_strided(const float* __restrict__ s, u16* __restrict__ d, int dld) {
  int t = blockIdx.x * blockDim.x + threadIdx.x;  // 524288 threads
  int b = t >> 8, j = (t & 255) << 2;
  float4 v = *(const float4*)(s + (size_t)b * 1024 + j);
  *(ushort4*)(d + (size_t)b * dld + j) = make_ushort4(f2bf(v.x), f2bf(v.y), f2bf(v.z), f2bf(v.w));
}

// pred -> both concat buffers
__global__ void conv_pred2(const float* __restrict__ s, u16* __restrict__ d1,
                           u16* __restrict__ d2) {
  int t = blockIdx.x * blockDim.x + threadIdx.x;
  int b = t >> 8, j = (t & 255) << 2;
  float4 v = *(const float4*)(s + (size_t)b * 1024 + j);
  ushort4 u = make_ushort4(f2bf(v.x), f2bf(v.y), f2bf(v.z), f2bf(v.w));
  *(ushort4*)(d1 + (size_t)b * 5120 + j) = u;
  *(ushort4*)(d2 + (size_t)b * 3072 + j) = u;
}

// input_t: convert into rcombined col 0..1023 AND write per-block var1 partial sums
__global__ void conv_var(const float* __restrict__ s, u16* __restrict__ d,
                         float* __restrict__ partials) {
  int t = blockIdx.x * blockDim.x + threadIdx.x;  // 524288 threads
  int b = t >> 8, j = (t & 255) << 2;
  float4 v = *(const float4*)(s + (size_t)b * 1024 + j);
  *(ushort4*)(d + (size_t)b * 3072 + j) = make_ushort4(f2bf(v.x), f2bf(v.y), f2bf(v.z), f2bf(v.w));
  float ls = v.x + v.y + v.z + v.w;
  float lq = v.x * v.x + v.y * v.y + v.z * v.z + v.w * v.w;
#pragma unroll
  for (int off = 32; off; off >>= 1) { ls += __shfl_down(ls, off); lq += __shfl_down(lq, off); }
  __shared__ float red[8];
  if ((threadIdx.x & 63) == 0) {
    int w = threadIdx.x >> 6;
    red[w] = ls; red[4 + w] = lq;
  }
  __syncthreads();
  if (threadIdx.x == 0) {
    partials[(size_t)blockIdx.x * 2]     = red[0] + red[1] + red[2] + red[3];
    partials[(size_t)blockIdx.x * 2 + 1] = red[4] + red[5] + red[6] + red[7];
  }
}

// AW = A_list * gc_W elementwise, to bf16
__global__ void make_AW(const float* __restrict__ a, const float* __restrict__ w,
                        u16* __restrict__ d, long n4) {
  long stride = (long)gridDim.x * blockDim.x;
  for (long i = blockIdx.x * (long)blockDim.x + threadIdx.x; i < n4; i += stride) {
    float4 va = *(const float4*)(a + i * 4);
    float4 vw = *(const float4*)(w + i * 4);
    *(ushort4*)(d + i * 4) = make_ushort4(f2bf(va.x * vw.x), f2bf(va.y * vw.y),
                                          f2bf(va.z * vw.z), f2bf(va.w * vw.w));
  }
}

// concat 8 bias vectors [1024] -> bias_g[4096] ++ bias_r[4096]
__global__ void cat8(const float* __restrict__ a, const float* __restrict__ b,
                     const float* __restrict__ c, const float* __restrict__ d,
                     const float* __restrict__ e, const float* __restrict__ f,
                     const float* __restrict__ g, const float* __restrict__ h,
                     float* __restrict__ og, float* __restrict__ orr) {
  int i = blockIdx.x * blockDim.x + threadIdx.x;  // 8192 threads
  int seg = i >> 10;
  const float* s = (seg == 0) ? a : (seg == 1) ? b : (seg == 2) ? c : (seg == 3) ? d
                 : (seg == 4) ? e : (seg == 5) ? f : (seg == 6) ? g : h;
  float v = s[i & 1023];
  if (i < 4096) og[i] = v; else orr[i - 4096] = v;
}

// nvec[m] = sum_n A3[m][n] * Nw[n]
__global__ void nvec_kernel(const float* __restrict__ A3, const float* __restrict__ Nw,
                            float* __restrict__ nvec) {
  int m = blockIdx.x, t = threadIdx.x;
  float s = 0.f;
  for (int c = t; c < 1024; c += 256) s += A3[(size_t)m * 1024 + c] * Nw[c];
  __shared__ float red[4];
#pragma unroll
  for (int off = 32; off; off >>= 1) s += __shfl_down(s, off);
  if ((t & 63) == 0) red[t >> 6] = s;
  __syncthreads();
  if (t == 0) nvec[m] = red[0] + red[1] + red[2] + red[3];
}

// fold per-block partials into sums[0..3] — single block, no atomics anywhere
__global__ void reduce_sums(const float* __restrict__ p1, int n1,
                            const float* __restrict__ p2, int n2,
                            float* __restrict__ sums) {
  float a = 0.f, b = 0.f, c = 0.f, d = 0.f;
  for (int i = threadIdx.x; i < n1; i += 256) { a += p1[2 * i]; b += p1[2 * i + 1]; }
  for (int i = threadIdx.x; i < n2; i += 256) { c += p2[2 * i]; d += p2[2 * i + 1]; }
#pragma unroll
  for (int off = 32; off; off >>= 1) {
    a += __shfl_down(a, off); b += __shfl_down(b, off);
    c += __shfl_down(c, off); d += __shfl_down(d, off);
  }
  __shared__ float red[16];
  if ((threadIdx.x & 63) == 0) {
    int w = threadIdx.x >> 6;
    red[w] = a; red[4 + w] = b; red[8 + w] = c; red[12 + w] = d;
  }
  __syncthreads();
  if (threadIdx.x == 0) {
    sums[0] = red[0] + red[1] + red[2] + red[3];
    sums[1] = red[4] + red[5] + red[6] + red[7];
    sums[2] = red[8] + red[9] + red[10] + red[11];
    sums[3] = red[12] + red[13] + red[14] + red[15];
  }
}

// ---------------------------------------------------------------- GEMM (C = A @ W^T, bf16 MFMA)
// A: [M][K] bf16 (lda), W: [Ncols][K] bf16 (ldw). Block tile 128x128, BK=64.
// 256 threads = 4 waves in 2x2, each wave 64x64 via 4x4 of 16x16x32 MFMA.
// MODE 0: gc epilogue (fp32 out + bf16 copy + per-block var2 partials), single-K.
// MODE 2: split-K bf16 partial output (blockIdx.z selects K-half; K param = half length).
template <int MODE>
__launch_bounds__(256)
__global__ void gemm_bt(const u16* __restrict__ A, int lda,
                        const u16* __restrict__ W, int ldw, int K,
                        float* __restrict__ out0, int ld0,
                        u16* __restrict__ outb, int ldb, size_t partStride,
                        float* __restrict__ partials) {
  __shared__ u16 lA[128 * 64];
  __shared__ u16 lB[128 * 64];
  const int tid = threadIdx.x;
  const int w = tid >> 6, l = tid & 63;
  const int bm = blockIdx.y << 7, bn = blockIdx.x << 7;
  const int waveM = ((w >> 1) & 1) << 6, waveN = (w & 1) << 6;
  const int quad = l >> 4, r16 = l & 15;

  // staging: each wave loads 32 rows of A-tile and 32 rows of B-tile, 4 issues of 8 rows
  // LDS dest = wave-uniform base + lane*16B; XOR-swizzle the fetched 16B chunk by row&7
  const int srow = l >> 3;            // row within 8-row chunk
  const int schunk = (l & 7) ^ srow;  // which global 16B chunk this lane fetches
  const u16* gA = A + (size_t)(bm + w * 32 + srow) * lda + schunk * 8;
  const u16* gB = W + (size_t)(bn + w * 32 + srow) * ldw + schunk * 8;
  u16* sA = lA + (w * 32) * 64;
  u16* sB = lB + (w * 32) * 64;

  f32x4 acc[4][4] = {};

  const int kBegin = (MODE == 2) ? blockIdx.z * K : 0;
  const int kEnd = kBegin + K;
  for (int k0 = kBegin; k0 < kEnd; k0 += 64) {
#pragma unroll
    for (int i = 0; i < 4; i++) {
      glds16(gA + (size_t)(i * 8) * lda + k0, sA + i * 8 * 64);
      glds16(gB + (size_t)(i * 8) * ldw + k0, sB + i * 8 * 64);
    }
    __syncthreads();
#pragma unroll
    for (int ks = 0; ks < 2; ks++) {
      bf16x8 av[4], bv[4];
#pragma unroll
      for (int mi = 0; mi < 4; mi++) {
        int row = waveM + mi * 16 + r16;
        int ch = (ks * 4 + quad) ^ (r16 & 7);
        av[mi] = *(const bf16x8*)(lA + row * 64 + ch * 8);
      }
#pragma unroll
      for (int ni = 0; ni < 4; ni++) {
        int row = waveN + ni * 16 + r16;
        int ch = (ks * 4 + quad) ^ (r16 & 7);
        bv[ni] = *(const bf16x8*)(lB + row * 64 + ch * 8);
      }
#pragma unroll
      for (int mi = 0; mi < 4; mi++)
#pragma unroll
        for (int ni = 0; ni < 4; ni++)
          acc[mi][ni] = __builtin_amdgcn_mfma_f32_16x16x32_bf16(av[mi], bv[ni], acc[mi][ni], 0, 0, 0);
    }
    __syncthreads();
  }

  // C/D layout: col = lane&15, row = (lane>>4)*4 + reg
  if constexpr (MODE == 0) {
    float ls = 0.f, lq = 0.f;
#pragma unroll
    for (int mi = 0; mi < 4; mi++)
#pragma unroll
      for (int ni = 0; ni < 4; ni++) {
        int col = bn + waveN + ni * 16 + r16;
#pragma unroll
        for (int e = 0; e < 4; e++) {
          int row = bm + waveM + mi * 16 + quad * 4 + e;
          float v = acc[mi][ni][e];
          out0[(size_t)row * ld0 + col] = v;
          outb[(size_t)row * ldb + col] = f2bf(v);
          ls += v;
          lq += v * v;
        }
      }
#pragma unroll
    for (int off = 32; off; off >>= 1) { ls += __shfl_down(ls, off); lq += __shfl_down(lq, off); }
    __shared__ float red[8];
    if (l == 0) { red[w] = ls; red[4 + w] = lq; }
    __syncthreads();
    if (tid == 0) {
      int bidx = blockIdx.y * gridDim.x + blockIdx.x;
      partials[(size_t)bidx * 2]     = red[0] + red[1] + red[2] + red[3];
      partials[(size_t)bidx * 2 + 1] = red[4] + red[5] + red[6] + red[7];
    }
  } else {
    u16* outz = outb + blockIdx.z * partStride;
#pragma unroll
    for (int mi = 0; mi < 4; mi++)
#pragma unroll
      for (int ni = 0; ni < 4; ni++) {
        int col = bn + waveN + ni * 16 + r16;
#pragma unroll
        for (int e = 0; e < 4; e++) {
          int row = bm + waveM + mi * 16 + quad * 4 + e;
          outz[(size_t)row * ldb + col] = f2bf(acc[mi][ni][e]);
        }
      }
  }
}

// ---------------------------------------------------------------- epilogue kernels
// read two bf16 split-K partials, add + bias + activation, then cell math

DEV float4 gate4(const u16* p0, const u16* p1, const float* bias, size_t base, int boff) {
  ushort4 a = *(const ushort4*)(p0 + base);
  ushort4 b = *(const ushort4*)(p1 + base);
  float4 bb = *(const float4*)(bias + boff);
  return make_float4(bf2f(a.x) + bf2f(b.x) + bb.x, bf2f(a.y) + bf2f(b.y) + bb.y,
                     bf2f(a.z) + bf2f(b.z) + bb.z, bf2f(a.w) + bf2f(b.w) + bb.w);
}
DEV float4 sig4(float4 v) {
  return make_float4(1.f / (1.f + __expf(-v.x)), 1.f / (1.f + __expf(-v.y)),
                     1.f / (1.f + __expf(-v.z)), 1.f / (1.f + __expf(-v.w)));
}
DEV float4 tanh4(float4 v) {
  return make_float4(tanhf(v.x), tanhf(v.y), tanhf(v.z), tanhf(v.w));
}

__global__ void cell_kernel(const u16* __restrict__ p0, const u16* __restrict__ p1,
                            const float* __restrict__ bias,
                            const float* __restrict__ CS, const float* __restrict__ nvec,
                            float* __restrict__ CellOut, float* __restrict__ Hid) {
  int t = blockIdx.x * blockDim.x + threadIdx.x;  // 524288
  int b = t >> 8, j = (t & 255) << 2;
  size_t rb = (size_t)b * 4096 + j;
  float4 f = sig4(gate4(p0, p1, bias, rb, j));
  float4 ii = sig4(gate4(p0, p1, bias, rb + 1024, 1024 + j));
  float4 o = sig4(gate4(p0, p1, bias, rb + 2048, 2048 + j));
  float4 C = tanh4(gate4(p0, p1, bias, rb + 3072, 3072 + j));
  float4 cs = *(const float4*)(CS + (size_t)b * 1024 + j);
  float4 nv = *(const float4*)(nvec + j);
  float4 cell, hid;
  cell.x = f.x * (cs.x * nv.x) + ii.x * C.x; hid.x = o.x * tanhf(cell.x);
  cell.y = f.y * (cs.y * nv.y) + ii.y * C.y; hid.y = o.y * tanhf(cell.y);
  cell.z = f.z * (cs.z * nv.z) + ii.z * C.z; hid.z = o.z * tanhf(cell.z);
  cell.w = f.w * (cs.w * nv.w) + ii.w * C.w; hid.w = o.w * tanhf(cell.w);
  *(float4*)(CellOut + (size_t)b * 1024 + j) = cell;
  *(float4*)(Hid + (size_t)b * 1024 + j) = hid;
}

__global__ void rcell_kernel(const u16* __restrict__ p0, const u16* __restrict__ p1,
                             const float* __restrict__ bias,
                             const float* __restrict__ rCS,
                             float* __restrict__ rCellOut, float* __restrict__ rHid) {
  int t = blockIdx.x * blockDim.x + threadIdx.x;
  int b = t >> 8, j = (t & 255) << 2;
  size_t rb = (size_t)b * 4096 + j;
  float4 f = sig4(gate4(p0, p1, bias, rb, j));
  float4 ii = sig4(gate4(p0, p1, bias, rb + 1024, 1024 + j));
  float4 o = sig4(gate4(p0, p1, bias, rb + 2048, 2048 + j));
  float4 C = tanh4(gate4(p0, p1, bias, rb + 3072, 3072 + j));
  float4 cs = *(const float4*)(rCS + (size_t)b * 1024 + j);
  float4 cell, hid;
  cell.x = f.x * cs.x + ii.x * C.x; hid.x = o.x * tanhf(cell.x);
  cell.y = f.y * cs.y + ii.y * C.y; hid.y = o.y * tanhf(cell.y);
  cell.z = f.z * cs.z + ii.z * C.z; hid.z = o.z * tanhf(cell.z);
  cell.w = f.w * cs.w + ii.w * C.w; hid.w = o.w * tanhf(cell.w);
  *(float4*)(rCellOut + (size_t)b * 1024 + j) = cell;
  *(float4*)(rHid + (size_t)b * 1024 + j) = hid;
}

__global__ void final_kernel(const float* __restrict__ Hid, const float* __restrict__ rHid,
                             const float* __restrict__ sums, const float* __restrict__ cp,
                             float* __restrict__ Hout, float* __restrict__ predOut,
                             float* __restrict__ rHout) {
  const float n1 = 2097152.f, n2 = 6291456.f;
  float var1 = (sums[1] - sums[0] * sums[0] / n1) / (n1 - 1.f);
  float var2 = (sums[3] - sums[2] * sums[2] / n2) / (n2 - 1.f);
  float c = cp[0];
  float inv = 1.f / (var1 + var2 * c);
  float s1 = var1 * c, s2 = var2;
  int t = blockIdx.x * blockDim.x + threadIdx.x;
  size_t i = (size_t)t << 2;
  float4 H = *(const float4*)(Hid + i);
  float4 R = *(const float4*)(rHid + i);
  float4 p, ho, rho;
  p.x = (H.x * s1 + R.x * s2) * inv; ho.x = H.x - p.x; rho.x = R.x - p.x;
  p.y = (H.y * s1 + R.y * s2) * inv; ho.y = H.y - p.y; rho.y = R.y - p.y;
  p.z = (H.z * s1 + R.z * s2) * inv; ho.z = H.z - p.z; rho.z = R.z - p.z;
  p.w = (H.w * s1 + R.w * s2) * inv; ho.w = H.w - p.w; rho.w = R.w - p.w;
  *(float4*)(predOut + i) = p;
  *(float4*)(Hout + i) = ho;
  *(float4*)(rHout + i) = rho;
}

// ---------------------------------------------------------------- launch

extern "C" void kernel_launch(void* const* d_in, const int* in_sizes, int n_in,
                              void* d_out, int out_size, void* d_ws, size_t ws_size,
                              hipStream_t stream) {
  const float* input   = (const float*)d_in[0];
  const float* input_t = (const float*)d_in[1];
  const float* HS      = (const float*)d_in[2];
  const float* CS      = (const float*)d_in[3];
  const float* rHS     = (const float*)d_in[4];
  const float* rCS     = (const float*)d_in[5];
  const float* pred    = (const float*)d_in[6];
  const float* A_list  = (const float*)d_in[7];
  const float* gc_W    = (const float*)d_in[8];
  const float* fl_W  = (const float*)d_in[9];  const float* fl_b  = (const float*)d_in[10];
  const float* il_W  = (const float*)d_in[11]; const float* il_b  = (const float*)d_in[12];
  const float* ol_W  = (const float*)d_in[13]; const float* ol_b  = (const float*)d_in[14];
  const float* Cl_W  = (const float*)d_in[15]; const float* Cl_b  = (const float*)d_in[16];
  const float* Nw    = (const float*)d_in[17];
  const float* rfl_W = (const float*)d_in[18]; const float* rfl_b = (const float*)d_in[19];
  const float* ril_W = (const float*)d_in[20]; const float* ril_b = (const float*)d_in[21];
  const float* rol_W = (const float*)d_in[22]; const float* rol_b = (const float*)d_in[23];
  const float* rCl_W = (const float*)d_in[24]; const float* rCl_b = (const float*)d_in[25];
  const float* cp    = (const float*)d_in[26];

  float* out      = (float*)d_out;
  float* Hout     = out;                // [2048][1024]
  float* CellOut  = out + 2097152;      // [2048][1024]
  float* gcOut    = out + 4194304;      // [2048][3072]
  float* rHout    = out + 10485760;     // [2048][1024]
  float* rCellOut = out + 12582912;     // [2048][1024]
  float* predOut  = out + 14680064;     // [2048][1024]

  // workspace carve-up (~150 MB)
  char* ws = (char*)d_ws;
  size_t off = 0;
  auto alloc = [&](size_t bytes) -> void* {
    void* p = ws + off;
    off = (off + bytes + 255) & ~(size_t)255;
    return p;
  };
  float* sums   = (float*)alloc(16);                           // var1 sum/sq, var2 sum/sq
  float* part1  = (float*)alloc(2048 * 2 * 4);                 // conv_var block partials
  float* part2  = (float*)alloc(384 * 2 * 4);                  // gemm1 block partials
  float* nvec   = (float*)alloc(1024 * 4);
  float* bias_g = (float*)alloc(4096 * 4);
  float* bias_r = (float*)alloc(4096 * 4);
  u16* comb  = (u16*)alloc((size_t)2048 * 5120 * 2);           // [gc | HS | pred] bf16
  u16* rcomb = (u16*)alloc((size_t)2048 * 3072 * 2);           // [input_t | rHS | pred] bf16
  u16* AW    = (u16*)alloc((size_t)3 * 1024 * 1024 * 2);       // masked gc weights bf16
  u16* gW    = (u16*)alloc((size_t)4096 * 5120 * 2);           // gate weights bf16
  u16* rW    = (u16*)alloc((size_t)4096 * 3072 * 2);           // r-gate weights bf16
  u16* gparts = (u16*)alloc((size_t)2 * 2048 * 4096 * 2);      // split-K bf16 gate partials
  float* Hid   = (float*)alloc((size_t)2048 * 1024 * 4);
  float* rHid  = (float*)alloc((size_t)2048 * 1024 * 4);
  // bA (input bf16, 4MB) aliases Hid (8MB): Hid is written only at cell_kernel,
  // after GEMM1 has consumed bA.
  u16* bA = (u16*)Hid;
  const size_t PSTRIDE = (size_t)2048 * 4096;

  conv_cat<<<2048, 256, 0, stream>>>(input, bA, 2048L * 1024 / 4);
  conv_var<<<2048, 256, 0, stream>>>(input_t, rcomb, part1);
  conv_strided<<<2048, 256, 0, stream>>>(HS, comb + 3072, 5120);
  conv_strided<<<2048, 256, 0, stream>>>(rHS, rcomb + 1024, 3072);
  conv_pred2<<<2048, 256, 0, stream>>>(pred, comb + 4096, rcomb + 2048);
  make_AW<<<2048, 256, 0, stream>>>(A_list, gc_W, AW, 3L * 1024 * 1024 / 4);
  wconv4<<<4 * 1280, 256, 0, stream>>>(fl_W, il_W, ol_W, Cl_W, gW, 1024L * 5120 / 4, 1280);
  wconv4<<<4 * 768, 256, 0, stream>>>(rfl_W, ril_W, rol_W, rCl_W, rW, 1024L * 3072 / 4, 768);
  cat8<<<32, 256, 0, stream>>>(fl_b, il_b, ol_b, Cl_b, rfl_b, ril_b, rol_b, rCl_b, bias_g, bias_r);
  nvec_kernel<<<1024, 256, 0, stream>>>(A_list + 2L * 1024 * 1024, Nw, nvec);

  // GEMM1: gc = input @ AW^T   [2048 x 3072], K=1024
  gemm_bt<0><<<dim3(24, 16), 256, 0, stream>>>(bA, 1024, AW, 1024, 1024,
                                               gcOut, 3072, comb, 5120, 0, part2);
  reduce_sums<<<1, 256, 0, stream>>>(part1, 2048, part2, 384, sums);
  // GEMM2: gate partials = combined @ gW^T  [2048 x 4096], split-K=2 (2x2560)
  gemm_bt<2><<<dim3(32, 16, 2), 256, 0, stream>>>(comb, 5120, gW, 5120, 2560,
                                                  nullptr, 0, gparts, 4096, PSTRIDE, nullptr);
  cell_kernel<<<2048, 256, 0, stream>>>(gparts, gparts + PSTRIDE, bias_g, CS, nvec, CellOut, Hid);
  // GEMM3: r-gate partials = rcombined @ rW^T  [2048 x 4096], split-K=2 (2x1536)
  gemm_bt<2><<<dim3(32, 16, 2), 256, 0, stream>>>(rcomb, 3072, rW, 3072, 1536,
                                                  nullptr, 0, gparts, 4096, PSTRIDE, nullptr);
  rcell_kernel<<<2048, 256, 0, stream>>>(gparts, gparts + PSTRIDE, bias_r, rCS, rCellOut, rHid);
  final_kernel<<<2048, 256, 0, stream>>>(Hid, rHid, sums, cp, Hout, predOut, rHout);

  (void)in_sizes; (void)n_in; (void)out_size; (void)ws_size;
}